// Round 1
// baseline (127.706 us; speedup 1.0000x reference)
//
#include <hip/hip_runtime.h>

// out[n] = relu(x[n] @ Wv + bv) * (node n has >=1 incoming edge ? 1 : 0)
// Softmax weights over each target-segment sum to exactly 1, and both the
// gather (x[tgt]) and the scatter use the SAME index, so the edge softmax
// cancels algebraically. Only edge_index row 1 matters (to detect empty
// segments -> output 0).

#define D_CH 96
#define TM 64          // rows per block
#define BLOCK_B 192    // 24 col-groups x 8 row-slots (3 waves)
#define XS_STRIDE 100  // 96 + 4 pad: keeps 16B alignment, de-aliases banks per row

__global__ void mark_targets_kernel(const int* __restrict__ tgt,
                                    int* __restrict__ flags, int E) {
    int i = blockIdx.x * blockDim.x + threadIdx.x;
    if (i < E) flags[tgt[i]] = 1;   // racy same-value store: benign
}

__global__ __launch_bounds__(BLOCK_B) void value_gemm_mask_kernel(
    const float* __restrict__ x, const float* __restrict__ Wv,
    const float* __restrict__ bv, const int* __restrict__ flags,
    float* __restrict__ out, int N)
{
    __shared__ float xs[TM * XS_STRIDE];   // 25.6 KB
    __shared__ float Wls[D_CH * D_CH];     // 36.9 KB (total 62.4 KB < 64 KB)

    const int t = threadIdx.x;
    const int row0 = blockIdx.x * TM;

    // stage Wv: flat 9216 floats = 2304 float4, 12 per thread, coalesced
    {
        const float4* src = (const float4*)Wv;
        float4*       dst = (float4*)Wls;
        #pragma unroll
        for (int it = 0; it < (D_CH * D_CH / 4) / BLOCK_B; ++it)
            dst[t + BLOCK_B * it] = src[t + BLOCK_B * it];
    }
    // stage x tile: TM rows x 24 float4, coalesced
    #pragma unroll
    for (int it = 0; it < (TM * 24) / BLOCK_B; ++it) {
        int f = t + BLOCK_B * it;
        int r = f / 24, cg = f % 24;
        int row = row0 + r;
        float4 v = make_float4(0.f, 0.f, 0.f, 0.f);
        if (row < N) v = *(const float4*)(x + (size_t)row * D_CH + cg * 4);
        *(float4*)(xs + r * XS_STRIDE + cg * 4) = v;
    }
    __syncthreads();

    const int c = t % 24;   // column group: cols 4c..4c+3
    const int g = t / 24;   // row slot: rows g, g+8, ..., g+56 (interleaved so
                            // same-wave g's map to disjoint LDS bank groups)

    float4 acc[8];
    #pragma unroll
    for (int r = 0; r < 8; ++r) acc[r] = make_float4(0.f, 0.f, 0.f, 0.f);

    #pragma unroll 4
    for (int kb = 0; kb < D_CH / 4; ++kb) {
        const float4 w0 = *(const float4*)(Wls + (4 * kb + 0) * D_CH + 4 * c);
        const float4 w1 = *(const float4*)(Wls + (4 * kb + 1) * D_CH + 4 * c);
        const float4 w2 = *(const float4*)(Wls + (4 * kb + 2) * D_CH + 4 * c);
        const float4 w3 = *(const float4*)(Wls + (4 * kb + 3) * D_CH + 4 * c);
        #pragma unroll
        for (int r = 0; r < 8; ++r) {
            const float4 xv = *(const float4*)(xs + (g + 8 * r) * XS_STRIDE + 4 * kb);
            acc[r].x += xv.x * w0.x + xv.y * w1.x + xv.z * w2.x + xv.w * w3.x;
            acc[r].y += xv.x * w0.y + xv.y * w1.y + xv.z * w2.y + xv.w * w3.y;
            acc[r].z += xv.x * w0.z + xv.y * w1.z + xv.z * w2.z + xv.w * w3.z;
            acc[r].w += xv.x * w0.w + xv.y * w1.w + xv.z * w2.w + xv.w * w3.w;
        }
    }

    const float4 bvv = *(const float4*)(bv + 4 * c);
    #pragma unroll
    for (int r = 0; r < 8; ++r) {
        const int row = row0 + g + 8 * r;
        if (row < N) {
            const float m = flags[row] ? 1.0f : 0.0f;
            float4 v;
            v.x = fmaxf(acc[r].x + bvv.x, 0.f) * m;
            v.y = fmaxf(acc[r].y + bvv.y, 0.f) * m;
            v.z = fmaxf(acc[r].z + bvv.z, 0.f) * m;
            v.w = fmaxf(acc[r].w + bvv.w, 0.f) * m;
            *(float4*)(out + (size_t)row * D_CH + 4 * c) = v;
        }
    }
}

extern "C" void kernel_launch(void* const* d_in, const int* in_sizes, int n_in,
                              void* d_out, int out_size, void* d_ws, size_t ws_size,
                              hipStream_t stream) {
    // inputs: 0=x [N*96], 1=p_t (unused), 2=Wv [96*96], 3=bv [96],
    //         4=edge_weights [E] (unused: softmax sums cancel), 5=edge_index [2*E]
    const float* x  = (const float*)d_in[0];
    const float* Wv = (const float*)d_in[2];
    const float* bv = (const float*)d_in[3];
    const int*   ei = (const int*)d_in[5];

    const int N = in_sizes[0] / D_CH;
    const int E = in_sizes[4];
    const int* tgt = ei + E;        // row 1 of edge_index [2, E]

    int* flags = (int*)d_ws;        // N ints of scratch
    hipMemsetAsync(flags, 0, (size_t)N * sizeof(int), stream);

    mark_targets_kernel<<<(E + 255) / 256, 256, 0, stream>>>(tgt, flags, E);

    const int blocks = (N + TM - 1) / TM;
    value_gemm_mask_kernel<<<blocks, BLOCK_B, 0, stream>>>(
        x, Wv, bv, flags, (float*)d_out, N);
}